// Round 1
// baseline (379.296 us; speedup 1.0000x reference)
//
#include <hip/hip_runtime.h>

#define T_TOK 16384
#define H_DIM 4096
#define O_DIM 4096
#define NA 8
#define RANK 16

// ---------------- sort-by-adapter machinery ----------------

__global__ void k_zero(int* __restrict__ counts) {
    if (threadIdx.x < NA) counts[threadIdx.x] = 0;
}

__global__ void k_hist(const int* __restrict__ idx, int* __restrict__ counts) {
    __shared__ int h[NA];
    if (threadIdx.x < NA) h[threadIdx.x] = 0;
    __syncthreads();
    int t = blockIdx.x * blockDim.x + threadIdx.x;
    atomicAdd(&h[idx[t]], 1);
    __syncthreads();
    if (threadIdx.x < NA) atomicAdd(&counts[threadIdx.x], h[threadIdx.x]);
}

__global__ void k_prefix(const int* __restrict__ counts, int* __restrict__ offs,
                         int* __restrict__ cursor) {
    if (threadIdx.x == 0) {
        int run = 0;
        for (int n = 0; n < NA; n++) { offs[n] = run; cursor[n] = run; run += counts[n]; }
    }
}

__global__ void k_scatter(const int* __restrict__ idx, int* __restrict__ cursor,
                          int* __restrict__ order) {
    int t = blockIdx.x * blockDim.x + threadIdx.x;
    int a = idx[t];
    int lane = threadIdx.x & 63;
    // wave-aggregated atomics: <=8 atomics per wave instead of 64
    for (int n = 0; n < NA; n++) {
        unsigned long long m = __ballot(a == n);
        if (m) {
            int leader = __ffsll((unsigned long long)m) - 1;
            int cnt = __popcll(m);
            int base = 0;
            if (lane == leader) base = atomicAdd(&cursor[n], cnt);
            base = __shfl(base, leader);
            if (a == n) {
                int rank = __popcll(m & ((1ull << lane) - 1ull));
                order[base + rank] = t;
            }
        }
    }
}

// ---------------- shrink: V[p] = x[order[p]] @ A[n] ----------------
// grid (1024, 8), block 256 = 4 waves; each wave: 4 tokens, lane covers h = lane (mod 64)

__global__ __launch_bounds__(256, 4) void k_shrink(
    const float* __restrict__ x, const float* __restrict__ lora_a,
    const int* __restrict__ order, const int* __restrict__ counts,
    const int* __restrict__ offs, float* __restrict__ V) {
    const int n = blockIdx.y;
    const int cnt = counts[n];
    const int base = blockIdx.x * 16;           // position base within segment
    if (base >= cnt) return;
    const int seg = offs[n];
    const int w = threadIdx.x >> 6, lane = threadIdx.x & 63;

    __shared__ float aT[RANK][512];             // transposed A chunk, 32 KB

    int tok[4];
#pragma unroll
    for (int i = 0; i < 4; i++) {
        int pi = base + w * 4 + i;
        tok[i] = order[seg + (pi < cnt ? pi : 0)];
    }

    float acc[4][RANK];
#pragma unroll
    for (int i = 0; i < 4; i++)
#pragma unroll
        for (int r = 0; r < RANK; r++) acc[i][r] = 0.f;

    const float* An = lora_a + (size_t)n * H_DIM * RANK;

    for (int c = 0; c < H_DIM / 512; c++) {
        // stage 512x16 chunk transposed: 2048 float4, 8 per thread
        const float4* src = (const float4*)(An + (size_t)c * 512 * RANK);
#pragma unroll
        for (int k = 0; k < 8; k++) {
            int f4 = k * 256 + threadIdx.x;
            float4 v4 = src[f4];
            int e0 = f4 * 4;
            int hrel = e0 >> 4;                 // 0..511
            int r0 = e0 & 15;                   // 0,4,8,12
            aT[r0 + 0][hrel] = v4.x;
            aT[r0 + 1][hrel] = v4.y;
            aT[r0 + 2][hrel] = v4.z;
            aT[r0 + 3][hrel] = v4.w;
        }
        __syncthreads();
#pragma unroll
        for (int m = 0; m < 8; m++) {
            int hl = m * 64 + lane;
            int h = c * 512 + hl;
            float xv[4];
#pragma unroll
            for (int i = 0; i < 4; i++) xv[i] = x[(size_t)tok[i] * H_DIM + h];
#pragma unroll
            for (int r = 0; r < RANK; r++) {
                float av = aT[r][hl];
#pragma unroll
                for (int i = 0; i < 4; i++) acc[i][r] = fmaf(xv[i], av, acc[i][r]);
            }
        }
        __syncthreads();
    }

    // cross-lane sum over the 64-way h split
#pragma unroll
    for (int off = 32; off > 0; off >>= 1)
#pragma unroll
        for (int i = 0; i < 4; i++)
#pragma unroll
            for (int r = 0; r < RANK; r++)
                acc[i][r] += __shfl_xor(acc[i][r], off);

    // lane L writes value (i = L>>4, r = L&15) — static-select to avoid scratch
    float outv = 0.f;
#pragma unroll
    for (int i = 0; i < 4; i++)
#pragma unroll
        for (int r = 0; r < RANK; r++)
            outv = (lane == i * 16 + r) ? acc[i][r] : outv;
    int pi = base + w * 4 + (lane >> 4);
    if (pi < cnt) V[(size_t)(seg + pi) * RANK + (lane & 15)] = outv;
}

// ---------------- expand: out[t] = result[t] + V[p] @ B[n] ----------------
// grid (4 o-chunks, 128 pos-chunks, 8 adapters), block 256; B slice lives in registers

__global__ __launch_bounds__(256, 4) void k_expand(
    const float* __restrict__ result, const float* __restrict__ lora_b,
    const float* __restrict__ V, const int* __restrict__ order,
    const int* __restrict__ counts, const int* __restrict__ offs,
    float* __restrict__ out) {
    const int n = blockIdx.z;
    const int cnt = counts[n];
    const int pbase = blockIdx.y * 128;
    if (pbase >= cnt) return;
    const int seg = offs[n];
    const int o0 = blockIdx.x * 1024 + threadIdx.x * 4;

    __shared__ float vlds[128 * RANK];          // 8 KB
    __shared__ int olds[128];

    const int pend = min(pbase + 128, cnt);
    const int np = pend - pbase;

    const float4* vsrc = (const float4*)(V + (size_t)(seg + pbase) * RANK);
    int nf4 = np * 4;
    for (int k = threadIdx.x; k < nf4; k += 256) ((float4*)vlds)[k] = vsrc[k];
    for (int k = threadIdx.x; k < np; k += 256) olds[k] = order[seg + pbase + k];

    float4 b[RANK];
    const float* Bn = lora_b + (size_t)n * RANK * O_DIM;
#pragma unroll
    for (int r = 0; r < RANK; r++)
        b[r] = *(const float4*)(Bn + (size_t)r * O_DIM + o0);

    __syncthreads();

    for (int p = 0; p < np; p++) {
        int t = olds[p];
        float va[RANK];
#pragma unroll
        for (int q = 0; q < 4; q++)
            *(float4*)&va[q * 4] = *(const float4*)&vlds[p * RANK + q * 4];
        size_t off = (size_t)t * O_DIM + o0;
        float4 acc = *(const float4*)(result + off);
#pragma unroll
        for (int r = 0; r < RANK; r++) {
            acc.x = fmaf(va[r], b[r].x, acc.x);
            acc.y = fmaf(va[r], b[r].y, acc.y);
            acc.z = fmaf(va[r], b[r].z, acc.z);
            acc.w = fmaf(va[r], b[r].w, acc.w);
        }
        *(float4*)(out + off) = acc;
    }
}

// ---------------- launch ----------------

extern "C" void kernel_launch(void* const* d_in, const int* in_sizes, int n_in,
                              void* d_out, int out_size, void* d_ws, size_t ws_size,
                              hipStream_t stream) {
    const float* result = (const float*)d_in[0];
    const float* x      = (const float*)d_in[1];
    const float* lora_a = (const float*)d_in[2];
    const float* lora_b = (const float*)d_in[3];
    const int*   aidx   = (const int*)d_in[4];
    float* out = (float*)d_out;

    float* V    = (float*)d_ws;                                   // 1 MB
    int* order  = (int*)((char*)d_ws + (size_t)T_TOK * RANK * 4); // 64 KB
    int* counts = order + T_TOK;
    int* offs   = counts + NA;
    int* cursor = offs + NA;

    k_zero<<<dim3(1), dim3(64), 0, stream>>>(counts);
    k_hist<<<dim3(64), dim3(256), 0, stream>>>(aidx, counts);
    k_prefix<<<dim3(1), dim3(64), 0, stream>>>(counts, offs, cursor);
    k_scatter<<<dim3(64), dim3(256), 0, stream>>>(aidx, cursor, order);
    k_shrink<<<dim3(1024, 8), dim3(256), 0, stream>>>(x, lora_a, order, counts, offs, V);
    k_expand<<<dim3(4, 128, 8), dim3(256), 0, stream>>>(result, lora_b, V, order, counts, offs, out);
}

// Round 2
// 284.354 us; speedup vs baseline: 1.3339x; 1.3339x over previous
//
#include <hip/hip_runtime.h>

#define T_TOK 16384
#define H_DIM 4096
#define O_DIM 4096
#define NA 8
#define RANK 16

// ---------------- sort-by-adapter machinery ----------------

__global__ void k_zero(int* __restrict__ counts) {
    if (threadIdx.x < NA) counts[threadIdx.x] = 0;
}

__global__ void k_hist(const int* __restrict__ idx, int* __restrict__ counts) {
    __shared__ int h[NA];
    if (threadIdx.x < NA) h[threadIdx.x] = 0;
    __syncthreads();
    int t = blockIdx.x * blockDim.x + threadIdx.x;
    atomicAdd(&h[idx[t]], 1);
    __syncthreads();
    if (threadIdx.x < NA) atomicAdd(&counts[threadIdx.x], h[threadIdx.x]);
}

__global__ void k_prefix(const int* __restrict__ counts, int* __restrict__ offs,
                         int* __restrict__ cursor) {
    if (threadIdx.x == 0) {
        int run = 0;
        for (int n = 0; n < NA; n++) { offs[n] = run; cursor[n] = run; run += counts[n]; }
    }
}

__global__ void k_scatter(const int* __restrict__ idx, int* __restrict__ cursor,
                          int* __restrict__ order) {
    int t = blockIdx.x * blockDim.x + threadIdx.x;
    int a = idx[t];
    int lane = threadIdx.x & 63;
    for (int n = 0; n < NA; n++) {
        unsigned long long m = __ballot(a == n);
        if (m) {
            int leader = __ffsll((unsigned long long)m) - 1;
            int cnt = __popcll(m);
            int base = 0;
            if (lane == leader) base = atomicAdd(&cursor[n], cnt);
            base = __shfl(base, leader);
            if (a == n) {
                int rank = __popcll(m & ((1ull << lane) - 1ull));
                order[base + rank] = t;
            }
        }
    }
}

// ---------------- transpose A -> AT[n][r][h] ----------------
// grid (16, 8), block 256. Coalesced f4 reads, LDS 2-way-free reads, coalesced writes.

__global__ void k_transpose(const float* __restrict__ A, float* __restrict__ AT) {
    const int n = blockIdx.y;
    const int h0 = blockIdx.x * 256;
    __shared__ float lds[256 * RANK];
    const float4* src = (const float4*)(A + ((size_t)n * H_DIM + h0) * RANK);
#pragma unroll
    for (int k = 0; k < 4; ++k)
        ((float4*)lds)[k * 256 + threadIdx.x] = src[k * 256 + threadIdx.x];
    __syncthreads();
    float* dst = AT + (size_t)n * RANK * H_DIM;
#pragma unroll
    for (int k = 0; k < RANK; ++k) {
        int hr = threadIdx.x;                  // r = k (constant per k) -> coalesced
        dst[(size_t)k * H_DIM + h0 + hr] = lds[hr * RANK + k];
    }
}

// ---------------- shrink: V[p] = x[order[p]] @ A[n]  (no LDS, pure streaming) ----------------
// grid (1024, 8), block 256 = 4 waves; wave handles 4 tokens; lane covers h = c*256 + lane*4

__global__ __launch_bounds__(256, 4) void k_shrink(
    const float* __restrict__ x, const float* __restrict__ at,
    const int* __restrict__ order, const int* __restrict__ counts,
    const int* __restrict__ offs, float* __restrict__ V) {
    const int n = blockIdx.y;
    const int cnt = counts[n];
    const int base = blockIdx.x * 16;
    if (base >= cnt) return;
    const int seg = offs[n];
    const int w = threadIdx.x >> 6, lane = threadIdx.x & 63;

    int tok[4];
#pragma unroll
    for (int i = 0; i < 4; i++) {
        int pi = base + w * 4 + i;
        tok[i] = order[seg + (pi < cnt ? pi : cnt - 1)];
    }

    float acc[4][RANK];
#pragma unroll
    for (int i = 0; i < 4; i++)
#pragma unroll
        for (int r = 0; r < RANK; r++) acc[i][r] = 0.f;

    const float* At = at + (size_t)n * RANK * H_DIM;   // [16][4096]

    for (int c = 0; c < H_DIM / 256; c++) {
        const int h = c * 256 + lane * 4;
        float4 xv[4];
#pragma unroll
        for (int i = 0; i < 4; i++)
            xv[i] = *(const float4*)(x + (size_t)tok[i] * H_DIM + h);
#pragma unroll
        for (int r = 0; r < RANK; r++) {
            float4 a4 = *(const float4*)(At + (size_t)r * H_DIM + h);
#pragma unroll
            for (int i = 0; i < 4; i++) {
                acc[i][r] = fmaf(xv[i].x, a4.x, acc[i][r]);
                acc[i][r] = fmaf(xv[i].y, a4.y, acc[i][r]);
                acc[i][r] = fmaf(xv[i].z, a4.z, acc[i][r]);
                acc[i][r] = fmaf(xv[i].w, a4.w, acc[i][r]);
            }
        }
    }

    // cross-lane sum over the 64-way h split
#pragma unroll
    for (int off = 32; off > 0; off >>= 1)
#pragma unroll
        for (int i = 0; i < 4; i++)
#pragma unroll
            for (int r = 0; r < RANK; r++)
                acc[i][r] += __shfl_xor(acc[i][r], off);

    // lane L writes value (i = L>>4, r = L&15) — static select, no scratch
    float outv = 0.f;
#pragma unroll
    for (int i = 0; i < 4; i++)
#pragma unroll
        for (int r = 0; r < RANK; r++)
            outv = (lane == i * 16 + r) ? acc[i][r] : outv;
    int pi = base + w * 4 + (lane >> 4);
    if (pi < cnt) V[(size_t)(seg + pi) * RANK + (lane & 15)] = outv;
}

// ---------------- expand: out[t] = result[t] + V[p] @ B[n] ----------------
// grid (4 o-chunks, 512 pos-chunks, 8 adapters), block 256; np=32 tokens/block
// B slice (16 x float4) in registers; 1-deep pipeline on the result load.

__global__ __launch_bounds__(256, 4) void k_expand(
    const float* __restrict__ result, const float* __restrict__ lora_b,
    const float* __restrict__ V, const int* __restrict__ order,
    const int* __restrict__ counts, const int* __restrict__ offs,
    float* __restrict__ out) {
    const int n = blockIdx.z;
    const int cnt = counts[n];
    const int pbase = blockIdx.y * 32;
    if (pbase >= cnt) return;
    const int seg = offs[n];
    const int o0 = blockIdx.x * 1024 + threadIdx.x * 4;

    __shared__ float vlds[32 * RANK];           // 2 KB
    __shared__ int olds[32];

    const int np = min(32, cnt - pbase);

    const float4* vsrc = (const float4*)(V + (size_t)(seg + pbase) * RANK);
    if (threadIdx.x < np * 4) ((float4*)vlds)[threadIdx.x] = vsrc[threadIdx.x];
    if (threadIdx.x < np) olds[threadIdx.x] = order[seg + pbase + threadIdx.x];

    float4 b[RANK];
    const float* Bn = lora_b + (size_t)n * RANK * O_DIM;
#pragma unroll
    for (int r = 0; r < RANK; r++)
        b[r] = *(const float4*)(Bn + (size_t)r * O_DIM + o0);

    __syncthreads();

    size_t off0 = (size_t)olds[0] * O_DIM + o0;
    float4 rv = *(const float4*)(result + off0);
    size_t offc = off0;

    for (int p = 0; p < np; p++) {
        // prefetch next token's result chunk
        float4 rv_next;
        size_t off_next = 0;
        if (p + 1 < np) {
            off_next = (size_t)olds[p + 1] * O_DIM + o0;
            rv_next = *(const float4*)(result + off_next);
        }
        float va[RANK];
#pragma unroll
        for (int q = 0; q < 4; q++)
            *(float4*)&va[q * 4] = *(const float4*)&vlds[p * RANK + q * 4];
        float4 acc = rv;
#pragma unroll
        for (int r = 0; r < RANK; r++) {
            acc.x = fmaf(va[r], b[r].x, acc.x);
            acc.y = fmaf(va[r], b[r].y, acc.y);
            acc.z = fmaf(va[r], b[r].z, acc.z);
            acc.w = fmaf(va[r], b[r].w, acc.w);
        }
        *(float4*)(out + offc) = acc;
        rv = rv_next;
        offc = off_next;
    }
}

// ---------------- launch ----------------

extern "C" void kernel_launch(void* const* d_in, const int* in_sizes, int n_in,
                              void* d_out, int out_size, void* d_ws, size_t ws_size,
                              hipStream_t stream) {
    const float* result = (const float*)d_in[0];
    const float* x      = (const float*)d_in[1];
    const float* lora_a = (const float*)d_in[2];
    const float* lora_b = (const float*)d_in[3];
    const int*   aidx   = (const int*)d_in[4];
    float* out = (float*)d_out;

    float* V    = (float*)d_ws;                                   // 1 MB
    int* order  = (int*)((char*)d_ws + (size_t)T_TOK * RANK * 4); // 64 KB
    int* counts = order + T_TOK;
    int* offs   = counts + NA;
    int* cursor = offs + NA;
    float* AT   = (float*)(cursor + NA);                          // 2 MB

    k_zero<<<dim3(1), dim3(64), 0, stream>>>(counts);
    k_hist<<<dim3(64), dim3(256), 0, stream>>>(aidx, counts);
    k_prefix<<<dim3(1), dim3(64), 0, stream>>>(counts, offs, cursor);
    k_scatter<<<dim3(64), dim3(256), 0, stream>>>(aidx, cursor, order);
    k_transpose<<<dim3(16, 8), dim3(256), 0, stream>>>(lora_a, AT);
    k_shrink<<<dim3(1024, 8), dim3(256), 0, stream>>>(x, AT, order, counts, offs, V);
    k_expand<<<dim3(4, 512, 8), dim3(256), 0, stream>>>(result, lora_b, V, order, counts, offs, out);
}